// Round 7
// baseline (249.558 us; speedup 1.0000x reference)
//
#include <hip/hip_runtime.h>
#include <hip/hip_bf16.h>
#include <cstdint>
#include <cstddef>
#include <math.h>

// Problem constants (reference: B=4096, D=256, T=0.5)
#define BSZ   4096
#define NROW  8192          // 2*B
#define DIM   256
#define INV_T 2.0f
#define EPS_N 1e-8f
#define CE    2.8853900817779268f   // INV_T * log2(e): e^(2x) = 2^(CE*x)
#define NTILE 2080                  // 64*65/2 upper-triangular 128-tiles

typedef __attribute__((ext_vector_type(8))) short bf16x8;   // 8 bf16 = 4 VGPRs
typedef __attribute__((ext_vector_type(4))) float f32x4;

// ---------------------------------------------------------------------------
// Compile-time tile schedule for XCD L2 locality (kept from R6: cuts HBM
// fetch 16.6->11 MB; perf-neutral but harmless, and kills the f64 decode).
struct TileOrder {
    unsigned short idx[NTILE];
    constexpr TileOrder() : idx{} {
        int pga[28] = {}, pgb[28] = {};
        int np = 0;
        for (int a = 0; a < 8; ++a)
            for (int b = a + 1; b < 8; ++b) { pga[np] = a; pgb[np] = b; ++np; }
        int seq[8][260] = {};
        for (int x = 0; x < 8; ++x) {
            int n = 0;
            for (int i = 0; i < 8; ++i)
                for (int j = i; j < 8; ++j)
                    seq[x][n++] = ((8 * x + i) << 8) | (8 * x + j);
            for (int p = 0; p < 3; ++p) {
                const int ga = pga[3 * x + p], gb = pgb[3 * x + p];
                for (int i = 0; i < 8; ++i)
                    for (int j = 0; j < 8; ++j)
                        seq[x][n++] = ((8 * ga + i) << 8) | (8 * gb + j);
            }
            const int pi = 24 + x / 2;
            const int ga = pga[pi], gb = pgb[pi];
            const int i0 = (x & 1) ? 4 : 0;
            for (int i = i0; i < i0 + 4; ++i)
                for (int j = 0; j < 8; ++j)
                    seq[x][n++] = ((8 * ga + i) << 8) | (8 * gb + j);
        }
        for (int l = 0; l < NTILE; ++l)
            idx[l] = (unsigned short)seq[l % 8][l / 8];
    }
};
__device__ constexpr TileOrder TO{};

__device__ __forceinline__ unsigned short f2bf(float x) {
    __hip_bfloat16 h = __float2bfloat16(x);
    return __builtin_bit_cast(unsigned short, h);
}
__device__ __forceinline__ float bf2f(unsigned short u) {
    __hip_bfloat16 h = __builtin_bit_cast(__hip_bfloat16, u);
    return __bfloat162float(h);
}

// async global->LDS 16B (wave-uniform LDS base + lane*16 layout)
__device__ __forceinline__ void load_lds16(const void* g, void* l) {
    __builtin_amdgcn_global_load_lds(
        (const __attribute__((address_space(1))) void*)g,
        (__attribute__((address_space(3))) void*)l,
        16, 0, 0);
}

// ---------------------------------------------------------------------------
// Kernel 1: row-normalize concat(z1,z2) -> bf16 zn; exact bf16 diag term
// sii[row] (finalize subtracts exp(2*sim_ii)); zeroes rowsum.
__global__ __launch_bounds__(256)
void nt_normalize(const float* __restrict__ z1,
                  const float* __restrict__ z2,
                  __hip_bfloat16* __restrict__ zn,
                  float* __restrict__ rowsum,
                  float* __restrict__ sii) {
    const int wave = threadIdx.x >> 6;
    const int lane = threadIdx.x & 63;
    const int row  = blockIdx.x * 4 + wave;
    const float* src = (row < BSZ) ? (z1 + (size_t)row * DIM)
                                   : (z2 + (size_t)(row - BSZ) * DIM);
    const float4 v = ((const float4*)src)[lane];
    float ss = v.x * v.x + v.y * v.y + v.z * v.z + v.w * v.w;
    #pragma unroll
    for (int off = 32; off; off >>= 1) ss += __shfl_xor(ss, off);
    const float rinv = 1.0f / fmaxf(sqrtf(ss), EPS_N);  // torch eps clamp
    ushort4 o;
    o.x = f2bf(v.x * rinv);
    o.y = f2bf(v.y * rinv);
    o.z = f2bf(v.z * rinv);
    o.w = f2bf(v.w * rinv);
    ((ushort4*)(zn + (size_t)row * DIM))[lane] = o;
    float bx = bf2f(o.x), by = bf2f(o.y), bz = bf2f(o.z), bw = bf2f(o.w);
    float s2 = bx * bx + by * by + bz * bz + bw * bw;
    #pragma unroll
    for (int off = 32; off; off >>= 1) s2 += __shfl_xor(s2, off);
    if (lane == 0) { sii[row] = s2; rowsum[row] = 0.0f; }
}

// ---------------------------------------------------------------------------
// Kernel 2: Zn·Znᵀ upper triangle, FULL-K staging: A strip (64 KB) + B strip
// in two K-halves (2x32 KB) = 128 KB LDS, only 2 barriers per block (vs 8),
// and the 2nd drain is pre-hidden (B1 issued before phase-0 compute).
// 512 threads = 8 waves (2 M-halves x 4 N-quarters, 64x32 wave-tiles).
// XOR-swizzled LDS: slot holds global chunk slot^(row&7) => fragment reads
// are 2-way/bank = free. Rowsum includes diagonal (finalize subtracts via
// sii); positives captured on the bj==bi+32 strip.
__global__ __launch_bounds__(512)
void nt_gram(const __hip_bfloat16* __restrict__ zn,
             float* __restrict__ rowsum,
             float* __restrict__ pos) {
    const int code = TO.idx[blockIdx.x];
    const int bi = code >> 8, bj = code & 255;

    __shared__ __hip_bfloat16 As[128 * 256];     // 64 KB: [128 rows][32 chunks x 16B]
    __shared__ __hip_bfloat16 Bs[2][128 * 128];  // 2x32 KB: [128 rows][16 chunks], K-halves

    const int t    = threadIdx.x;
    const int lane = t & 63;
    const int wave = t >> 6;        // 0..7
    const int wm   = wave >> 2;     // 0..1  M half (64 rows)
    const int wn   = wave & 3;      // 0..3  N quarter (32 cols)
    const int q    = lane >> 4;
    const int r16  = lane & 15;

    const __hip_bfloat16* Ag = zn + (size_t)bi * 128 * DIM;
    const __hip_bfloat16* Bg = zn + (size_t)bj * 128 * DIM;

    // Staging maps (identity LDS layout required by global_load_lds; swizzle
    // applied on the GLOBAL chunk index).
    const int srowA = t >> 5, slotA = t & 31;
    const int chA   = slotA ^ (srowA & 7);       // (p*16+srowA)&7 == srowA&7
    const int srowB = t >> 4, slotB = t & 15;
    const int chB   = slotB ^ (srowB & 7);       // (p*32+srowB)&7 == srowB&7

    #pragma unroll
    for (int p = 0; p < 8; ++p)                  // A: full K, 8 passes x 16 rows
        load_lds16(Ag + (size_t)(p * 16 + srowA) * DIM + chA * 8,
                   (char*)As + p * 8192 + t * 16);
    #pragma unroll
    for (int p = 0; p < 4; ++p)                  // B half 0 (k 0..127)
        load_lds16(Bg + (size_t)(p * 32 + srowB) * DIM + chB * 8,
                   (char*)Bs[0] + p * 8192 + t * 16);
    __syncthreads();                             // barrier 1: drains A + B0
    #pragma unroll
    for (int p = 0; p < 4; ++p)                  // B half 1 (k 128..255), flies
        load_lds16(Bg + (size_t)(p * 32 + srowB) * DIM + 128 + chB * 8,
                   (char*)Bs[1] + p * 8192 + t * 16);

    f32x4 acc[4][2] = {};

    #pragma unroll
    for (int h = 0; h < 2; ++h) {
        if (h == 1) __syncthreads();             // barrier 2: B1 landed long ago
        #pragma unroll
        for (int kkl = 0; kkl < 4; ++kkl) {
            const int ccA = (h * 4 + kkl) * 4 + q;   // A chunk 0..31
            const int ccB = kkl * 4 + q;             // B chunk 0..15 (per half)
            bf16x8 af[4], bfr[2];
            #pragma unroll
            for (int mi = 0; mi < 4; ++mi) {
                const int m = wm * 64 + mi * 16 + r16;
                af[mi] = *(const bf16x8*)((const char*)As + m * 512 +
                                          ((ccA ^ (m & 7)) << 4));
            }
            #pragma unroll
            for (int ni = 0; ni < 2; ++ni) {
                const int n = wn * 32 + ni * 16 + r16;
                bfr[ni] = *(const bf16x8*)((const char*)Bs[h] + n * 256 +
                                           ((ccB ^ (n & 7)) << 4));
            }
            #pragma unroll
            for (int mi = 0; mi < 4; ++mi)
                #pragma unroll
                for (int ni = 0; ni < 2; ++ni)
                    acc[mi][ni] = __builtin_amdgcn_mfma_f32_16x16x32_bf16(
                        af[mi], bfr[ni], acc[mi][ni], 0, 0, 0);
        }
    }

    // Epilogue. C/D layout: col=lane&15, row=(lane>>4)*4+reg (m89-verified).
    const int c = r16;
    f32x4 ev[4][2];
    #pragma unroll
    for (int mi = 0; mi < 4; ++mi)
        #pragma unroll
        for (int ni = 0; ni < 2; ++ni)
            #pragma unroll
            for (int r = 0; r < 4; ++r)
                ev[mi][ni][r] = exp2f(acc[mi][ni][r] * CE);

    // Row sums: butterfly over the 16 c-lanes, vectorized over the 4 regs
    // (4 parallel shfl chains instead of 1 -> 4x less dep latency).
    #pragma unroll
    for (int mi = 0; mi < 4; ++mi) {
        f32x4 rv = ev[mi][0] + ev[mi][1];
        #pragma unroll
        for (int off = 1; off <= 8; off <<= 1)
            #pragma unroll
            for (int r = 0; r < 4; ++r)
                rv[r] += __shfl_xor(rv[r], off);
        if (c == 0) {
            const int g0 = bi * 128 + wm * 64 + mi * 16 + q * 4;
            atomicAdd(&rowsum[g0 + 0], rv[0]);
            atomicAdd(&rowsum[g0 + 1], rv[1]);
            atomicAdd(&rowsum[g0 + 2], rv[2]);
            atomicAdd(&rowsum[g0 + 3], rv[3]);
        }
    }
    // Column sums feed the bj strip by symmetry; skip on diagonal tiles.
    if (bi != bj) {
        #pragma unroll
        for (int ni = 0; ni < 2; ++ni) {
            f32x4 cv = ev[0][ni] + ev[1][ni] + ev[2][ni] + ev[3][ni];
            float cs = cv[0] + cv[1] + cv[2] + cv[3];
            cs += __shfl_xor(cs, 16);
            cs += __shfl_xor(cs, 32);
            if (q == 0)
                atomicAdd(&rowsum[bj * 128 + wn * 32 + ni * 16 + c], cs);
        }
    }
    // Positives: bj == bi+32 strip; tile-local diagonal sits in waves with
    // wm == wn>>1, at mi == (wn&1)*2+ni, lanes with c == q*4+r.
    if (bj == bi + 32 && wm == (wn >> 1)) {
        #pragma unroll
        for (int ni = 0; ni < 2; ++ni) {
            const int mi = (wn & 1) * 2 + ni;
            #pragma unroll
            for (int r = 0; r < 4; ++r)
                if (c == q * 4 + r) {
                    const int grow = bi * 128 + wm * 64 + mi * 16 + q * 4 + r;
                    const float val = acc[mi][ni][r];
                    pos[grow] = val;
                    pos[grow + BSZ] = val;
                }
        }
    }
}

// ---------------------------------------------------------------------------
// Kernel 3: single block; subtract diagonal, add positive, reduce, write out.
__global__ __launch_bounds__(1024)
void nt_finalize(const float* __restrict__ rowsum,
                 const float* __restrict__ pos,
                 const float* __restrict__ sii,
                 float* __restrict__ out) {
    float v = 0.f;
    for (int i = threadIdx.x; i < NROW; i += 1024) {
        const float pl  = pos[i] * INV_T;
        const float neg = rowsum[i] - exp2f(sii[i] * CE);  // drop diagonal
        v += logf(__expf(pl) + neg) - pl;
    }
    #pragma unroll
    for (int off = 32; off; off >>= 1) v += __shfl_xor(v, off);
    __shared__ float red[16];
    if ((threadIdx.x & 63) == 0) red[threadIdx.x >> 6] = v;
    __syncthreads();
    if (threadIdx.x == 0) {
        float s = 0.f;
        #pragma unroll
        for (int w = 0; w < 16; ++w) s += red[w];
        out[0] = s * (1.0f / NROW);
    }
}

// ---------------------------------------------------------------------------
extern "C" void kernel_launch(void* const* d_in, const int* in_sizes, int n_in,
                              void* d_out, int out_size, void* d_ws, size_t ws_size,
                              hipStream_t stream) {
    const float* z1 = (const float*)d_in[0];
    const float* z2 = (const float*)d_in[1];
    float* out = (float*)d_out;

    __hip_bfloat16* zn = (__hip_bfloat16*)d_ws;                       // 4 MB
    float* rowsum = (float*)((char*)d_ws + (size_t)NROW * DIM * 2);   // 32 KB
    float* pos    = rowsum + NROW;                                    // 32 KB (fully written by gram)
    float* sii    = pos + NROW;                                       // 32 KB

    nt_normalize<<<NROW / 4, 256, 0, stream>>>(z1, z2, zn, rowsum, sii);
    nt_gram<<<NTILE, 512, 0, stream>>>(zn, rowsum, pos);
    nt_finalize<<<1, 1024, 0, stream>>>(rowsum, pos, sii, out);
}

// Round 8
// 120.393 us; speedup vs baseline: 2.0729x; 2.0729x over previous
//
#include <hip/hip_runtime.h>
#include <hip/hip_bf16.h>
#include <cstdint>
#include <cstddef>
#include <math.h>

// Problem constants (reference: B=4096, D=256, T=0.5)
#define BSZ   4096
#define NROW  8192          // 2*B
#define DIM   256
#define INV_T 2.0f
#define EPS_N 1e-8f
#define CE    2.8853900817779268f   // INV_T * log2(e): e^(2x) = 2^(CE*x)
#define NTILE 2080                  // 64*65/2 upper-triangular 128-tiles
#define GRID  520                   // persistent: 4 tiles/block, 2 blocks/CU

typedef __attribute__((ext_vector_type(8))) short bf16x8;   // 8 bf16 = 4 VGPRs
typedef __attribute__((ext_vector_type(4))) float f32x4;

// Row-major triangular tile table (kills the f64 sqrt decode). Block bid
// owns tiles bid*4..bid*4+3 — usually the same bi strip (L2 reuse of A).
struct TileOrder {
    unsigned short idx[NTILE];
    constexpr TileOrder() : idx{} {
        int n = 0;
        for (int bi = 0; bi < 64; ++bi)
            for (int bj = bi; bj < 64; ++bj)
                idx[n++] = (unsigned short)((bi << 8) | bj);
    }
};
__device__ constexpr TileOrder TO{};

__device__ __forceinline__ unsigned short f2bf(float x) {
    __hip_bfloat16 h = __float2bfloat16(x);
    return __builtin_bit_cast(unsigned short, h);
}
__device__ __forceinline__ float bf2f(unsigned short u) {
    __hip_bfloat16 h = __builtin_bit_cast(__hip_bfloat16, u);
    return __bfloat162float(h);
}

// async global->LDS 16B (wave-uniform LDS base + lane*16 layout)
__device__ __forceinline__ void load_lds16(const void* g, void* l) {
    __builtin_amdgcn_global_load_lds(
        (const __attribute__((address_space(1))) void*)g,
        (__attribute__((address_space(3))) void*)l,
        16, 0, 0);
}

// ---------------------------------------------------------------------------
// Kernel 1: row-normalize concat(z1,z2) -> bf16 zn; exact bf16 diag term
// sii[row] (finalize subtracts exp(2*sim_ii)); zeroes rowsum.
__global__ __launch_bounds__(256)
void nt_normalize(const float* __restrict__ z1,
                  const float* __restrict__ z2,
                  __hip_bfloat16* __restrict__ zn,
                  float* __restrict__ rowsum,
                  float* __restrict__ sii) {
    const int wave = threadIdx.x >> 6;
    const int lane = threadIdx.x & 63;
    const int row  = blockIdx.x * 4 + wave;
    const float* src = (row < BSZ) ? (z1 + (size_t)row * DIM)
                                   : (z2 + (size_t)(row - BSZ) * DIM);
    const float4 v = ((const float4*)src)[lane];
    float ss = v.x * v.x + v.y * v.y + v.z * v.z + v.w * v.w;
    #pragma unroll
    for (int off = 32; off; off >>= 1) ss += __shfl_xor(ss, off);
    const float rinv = 1.0f / fmaxf(sqrtf(ss), EPS_N);  // torch eps clamp
    ushort4 o;
    o.x = f2bf(v.x * rinv);
    o.y = f2bf(v.y * rinv);
    o.z = f2bf(v.z * rinv);
    o.w = f2bf(v.w * rinv);
    ((ushort4*)(zn + (size_t)row * DIM))[lane] = o;
    float bx = bf2f(o.x), by = bf2f(o.y), bz = bf2f(o.z), bw = bf2f(o.w);
    float s2 = bx * bx + by * by + bz * bz + bw * bw;
    #pragma unroll
    for (int off = 32; off; off >>= 1) s2 += __shfl_xor(s2, off);
    if (lane == 0) { sii[row] = s2; rowsum[row] = 0.0f; }
}

// ---------------------------------------------------------------------------
// Kernel 2: persistent-block Zn·Znᵀ, upper triangle. Each block: 4 tiles x
// 4 K-chunks = 16 flat stages, ping-pong 32 KB LDS buffers, ONE barrier per
// stage: sync -> issue loads(s+1) -> compute(s). The compiler's vmcnt(0)
// drain before s_barrier then only waits on loads that had a full compute
// phase in flight (steady-state drain ~0). Wave layout / swizzle / epilogue
// identical to the R6-verified kernel.
__global__ __launch_bounds__(256, 2)
void nt_gram(const __hip_bfloat16* __restrict__ zn,
             float* __restrict__ rowsum,
             float* __restrict__ pos) {
    // 2 buffers x (A 16 KB + B 16 KB)
    __shared__ __hip_bfloat16 smem[2][2][128 * 64];   // [par][A/B][128r x 8ch x 8]

    const int t    = threadIdx.x;
    const int lane = t & 63;
    const int wave = t >> 6;
    const int wrow = (wave >> 1) * 64;
    const int wcol = (wave & 1) * 64;
    const int q    = lane >> 4;
    const int r16  = lane & 15;
    const int sw   = r16 & 7;                 // read-side swizzle key

    const int srow = t >> 3;                  // 0..31 per pass
    const int sc   = (t & 7) ^ (srow & 7);    // swizzled global chunk (pass-inv)

    int codes[4];
    #pragma unroll
    for (int u = 0; u < 4; ++u) codes[u] = TO.idx[blockIdx.x * 4 + u];

    // stage issuer: tile code, K-chunk kc, buffer par
    auto issue = [&](int code, int kc, int par) {
        const __hip_bfloat16* Ag = zn + (size_t)(code >> 8) * 128 * DIM + kc * 64;
        const __hip_bfloat16* Bg = zn + (size_t)(code & 255) * 128 * DIM + kc * 64;
        #pragma unroll
        for (int p = 0; p < 4; ++p) {
            const int row = p * 32 + srow;
            load_lds16(Ag + (size_t)row * DIM + sc * 8,
                       (char*)smem[par][0] + p * 4096 + t * 16);
            load_lds16(Bg + (size_t)row * DIM + sc * 8,
                       (char*)smem[par][1] + p * 4096 + t * 16);
        }
    };

    f32x4 acc[4][4] = {};
    issue(codes[0], 0, 0);                    // prologue: stage 0 -> buf 0

    for (int u = 0; u < 4; ++u) {
        const int code = codes[u];
        const int bi = code >> 8, bj = code & 255;

        #pragma unroll
        for (int kc = 0; kc < 4; ++kc) {
            __syncthreads();                  // buf[kc&1] landed; readers of
                                              // buf[(kc+1)&1] (prev stage) done
            const int s = u * 4 + kc;
            if (s + 1 < 16)                   // prefetch next stage
                issue(codes[(s + 1) >> 2], (s + 1) & 3, (kc + 1) & 1);

            const char* As = (const char*)smem[kc & 1][0];
            const char* Bs = (const char*)smem[kc & 1][1];
            #pragma unroll
            for (int kk = 0; kk < 64; kk += 32) {
                const int cc = (kk >> 3) + q;          // chunk in row, 0..7
                const int cpos = (cc ^ sw) << 4;       // swizzled byte pos
                bf16x8 af[4], bfr[4];
                #pragma unroll
                for (int mi = 0; mi < 4; ++mi) {
                    const int m = wrow + mi * 16 + r16;
                    af[mi] = *(const bf16x8*)(As + m * 128 + cpos);
                }
                #pragma unroll
                for (int ni = 0; ni < 4; ++ni) {
                    const int n = wcol + ni * 16 + r16;
                    bfr[ni] = *(const bf16x8*)(Bs + n * 128 + cpos);
                }
                #pragma unroll
                for (int mi = 0; mi < 4; ++mi)
                    #pragma unroll
                    for (int ni = 0; ni < 4; ++ni)
                        acc[mi][ni] = __builtin_amdgcn_mfma_f32_16x16x32_bf16(
                            af[mi], bfr[ni], acc[mi][ni], 0, 0, 0);
            }
        }

        // ---- tile epilogue (overlaps next tile's in-flight prefetch) ----
        // C/D layout: col=lane&15, row=(lane>>4)*4+reg (m89-verified).
        const int c = r16;
        float colp[4] = {0.f, 0.f, 0.f, 0.f};
        #pragma unroll
        for (int mi = 0; mi < 4; ++mi) {
            #pragma unroll
            for (int r = 0; r < 4; ++r) {
                float s = 0.f;
                #pragma unroll
                for (int ni = 0; ni < 4; ++ni) {
                    const float e = exp2f(acc[mi][ni][r] * CE);
                    s += e;
                    colp[ni] += e;
                }
                s += __shfl_xor(s, 1);
                s += __shfl_xor(s, 2);
                s += __shfl_xor(s, 4);
                s += __shfl_xor(s, 8);
                if (c == 0) {
                    const int grow = bi * 128 + wrow + mi * 16 + q * 4 + r;
                    atomicAdd(&rowsum[grow], s);
                }
            }
        }
        if (bi != bj) {   // column sums feed the bj strip by symmetry
            #pragma unroll
            for (int ni = 0; ni < 4; ++ni) {
                float cs = colp[ni];
                cs += __shfl_xor(cs, 16);
                cs += __shfl_xor(cs, 32);
                if (q == 0) atomicAdd(&rowsum[bj * 128 + wcol + ni * 16 + c], cs);
            }
        }
        // Positives: bj==bi+32 strip, wrow==wcol waves, c==q*4+r lanes.
        if (bj == bi + 32 && wrow == wcol) {
            #pragma unroll
            for (int mi = 0; mi < 4; ++mi)
                #pragma unroll
                for (int r = 0; r < 4; ++r)
                    if (c == q * 4 + r) {
                        const int grow = bi * 128 + wrow + mi * 16 + q * 4 + r;
                        const float val = acc[mi][mi][r];
                        pos[grow] = val;
                        pos[grow + BSZ] = val;
                    }
        }
        #pragma unroll
        for (int mi = 0; mi < 4; ++mi)
            #pragma unroll
            for (int ni = 0; ni < 4; ++ni)
                acc[mi][ni] = f32x4{0.f, 0.f, 0.f, 0.f};
    }
}

// ---------------------------------------------------------------------------
// Kernel 3: single block; subtract diagonal, add positive, reduce, write out.
__global__ __launch_bounds__(1024)
void nt_finalize(const float* __restrict__ rowsum,
                 const float* __restrict__ pos,
                 const float* __restrict__ sii,
                 float* __restrict__ out) {
    float v = 0.f;
    for (int i = threadIdx.x; i < NROW; i += 1024) {
        const float pl  = pos[i] * INV_T;
        const float neg = rowsum[i] - exp2f(sii[i] * CE);  // drop diagonal
        v += logf(__expf(pl) + neg) - pl;
    }
    #pragma unroll
    for (int off = 32; off; off >>= 1) v += __shfl_xor(v, off);
    __shared__ float red[16];
    if ((threadIdx.x & 63) == 0) red[threadIdx.x >> 6] = v;
    __syncthreads();
    if (threadIdx.x == 0) {
        float s = 0.f;
        #pragma unroll
        for (int w = 0; w < 16; ++w) s += red[w];
        out[0] = s * (1.0f / NROW);
    }
}

// ---------------------------------------------------------------------------
extern "C" void kernel_launch(void* const* d_in, const int* in_sizes, int n_in,
                              void* d_out, int out_size, void* d_ws, size_t ws_size,
                              hipStream_t stream) {
    const float* z1 = (const float*)d_in[0];
    const float* z2 = (const float*)d_in[1];
    float* out = (float*)d_out;

    __hip_bfloat16* zn = (__hip_bfloat16*)d_ws;                       // 4 MB
    float* rowsum = (float*)((char*)d_ws + (size_t)NROW * DIM * 2);   // 32 KB
    float* pos    = rowsum + NROW;                                    // 32 KB (fully written by gram)
    float* sii    = pos + NROW;                                       // 32 KB

    nt_normalize<<<NROW / 4, 256, 0, stream>>>(z1, z2, zn, rowsum, sii);
    nt_gram<<<GRID, 256, 0, stream>>>(zn, rowsum, pos);
    nt_finalize<<<1, 1024, 0, stream>>>(rowsum, pos, sii, out);
}